// Round 14
// baseline (253.809 us; speedup 1.0000x reference)
//
#include <hip/hip_runtime.h>

#define BLK    256
#define NH     1024        // histogram/scatter grid blocks (== colscan threads)
#define SHIFT  11
#define CHUNK  2048        // nodes per bin = 1<<SHIFT (8 KB LDS accumulator)
#define BPB    32          // agg blocks per bin
#define MAXNB  256

// ---------------------------------------------------------------------------
// GCN 1->16->1 == scalar message passing (derivation r0).
// r13 counters: scatter/hist fixed (out of top-5). 3x k_bagg @42us each is
// the controllable bottleneck (VALUBusy 2.9%, occ 43%, HBM 8%); bagg<false>
// == bagg<true> time -> pk-load latency chain, NOT gather/LDS atomics.
// (Also: harness's 256MiB d_ws re-poison = 42us fill, uncontrollable floor.)
// r14: int4 batch loads of pk in bagg -> 4 independent chains/thread/iter
// (4x MLP). pk carve 16B-aligned; scalar head/tail at slice boundaries.
// Zero global atomics. Fallback to direct-atomic path if ws short.
// ---------------------------------------------------------------------------

// ---------- binned path ----------

__global__ void k_hist(const int* __restrict__ col, int* __restrict__ hist,
                       int E, int NB) {
    __shared__ int h[MAXNB];
    for (int j = threadIdx.x; j < NB; j += BLK) h[j] = 0;
    __syncthreads();
    int G = E >> 2;
    int stride = gridDim.x * blockDim.x;
    for (int g = blockIdx.x * blockDim.x + threadIdx.x; g < G; g += stride) {
        int4 c = reinterpret_cast<const int4*>(col)[g];
        atomicAdd(&h[c.x >> SHIFT], 1);
        atomicAdd(&h[c.y >> SHIFT], 1);
        atomicAdd(&h[c.z >> SHIFT], 1);
        atomicAdd(&h[c.w >> SHIFT], 1);
    }
    __syncthreads();
    for (int j = threadIdx.x; j < NB; j += BLK)
        hist[blockIdx.x * NB + j] = h[j];
}

// block p: exclusive scan over hist[0..NH)[p]; totals[p] = column sum
__global__ void k_colscan(const int* __restrict__ hist, int* __restrict__ colOff,
                          int* __restrict__ totals, int NB) {
    __shared__ int lds[NH];
    int p = blockIdx.x, t = threadIdx.x;
    int v = hist[t * NB + p];
    lds[t] = v;
    __syncthreads();
    for (int off = 1; off < NH; off <<= 1) {
        int add = (t >= off) ? lds[t - off] : 0;
        __syncthreads();
        lds[t] += add;
        __syncthreads();
    }
    colOff[t * NB + p] = lds[t] - v;                // exclusive
    if (t == NH - 1) totals[p] = lds[t];
}

// parallel exclusive scan over NB bin totals (NB <= MAXNB)
__global__ void k_binscan(const int* __restrict__ totals, int* __restrict__ binstart,
                          int NB) {
    __shared__ int lds[MAXNB];
    int t = threadIdx.x;
    int v = (t < NB) ? totals[t] : 0;
    lds[t] = v;
    __syncthreads();
    for (int off = 1; off < MAXNB; off <<= 1) {
        int add = (t >= off) ? lds[t - off] : 0;
        __syncthreads();
        lds[t] += add;
        __syncthreads();
    }
    if (t < NB) binstart[t] = lds[t] - v;
    if (t == NB - 1) binstart[NB] = lds[t];
}

// same grid + same traversal as k_hist => per-block quotas match.
// packs edge -> single int: (row << SHIFT) | (col & (CHUNK-1))
__global__ void k_scatter(const int* __restrict__ row, const int* __restrict__ col,
                          const int* __restrict__ colOff, const int* __restrict__ binstart,
                          int* __restrict__ pk, int E, int NB) {
    __shared__ int cur[MAXNB];
    for (int j = threadIdx.x; j < NB; j += BLK)
        cur[j] = binstart[j] + colOff[blockIdx.x * NB + j];
    __syncthreads();
    int G = E >> 2;
    int stride = gridDim.x * blockDim.x;
    for (int g = blockIdx.x * blockDim.x + threadIdx.x; g < G; g += stride) {
        int4 r = reinterpret_cast<const int4*>(row)[g];
        int4 c = reinterpret_cast<const int4*>(col)[g];
        int p0 = atomicAdd(&cur[c.x >> SHIFT], 1);
        int p1 = atomicAdd(&cur[c.y >> SHIFT], 1);
        int p2 = atomicAdd(&cur[c.z >> SHIFT], 1);
        int p3 = atomicAdd(&cur[c.w >> SHIFT], 1);
        pk[p0] = (r.x << SHIFT) | (c.x & (CHUNK - 1));
        pk[p1] = (r.y << SHIFT) | (c.y & (CHUNK - 1));
        pk[p2] = (r.z << SHIFT) | (c.z & (CHUNK - 1));
        pk[p3] = (r.w << SHIFT) | (c.w & (CHUNK - 1));
    }
}

// bin p = blockIdx/BPB, slice q = blockIdx%BPB; LDS-accumulate, flush partials.
// int4 batch loads of pk: 4 independent gather+ds_add chains per iteration.
template <bool GATHER>
__global__ void __launch_bounds__(BLK)
k_bagg(const int* __restrict__ pk, const int* __restrict__ binstart,
       const float* __restrict__ src, float* __restrict__ partial) {
    __shared__ float acc[CHUNK];
    int p = blockIdx.x / BPB, q = blockIdx.x % BPB;
    for (int j = threadIdx.x; j < CHUNK; j += BLK) acc[j] = 0.0f;
    __syncthreads();
    int s = binstart[p], t = binstart[p + 1];
    long long len = t - s;
    int lo = s + (int)(len * q / BPB);
    int hi = s + (int)(len * (q + 1) / BPB);

    int lo4 = (lo + 3) & ~3;
    int head_end = (lo4 < hi) ? lo4 : hi;
    int hi4 = hi & ~3;

    // scalar head (<=3 edges, aligns pk+lo4 to 16B)
    if (threadIdx.x < head_end - lo) {
        int v = pk[lo + threadIdx.x];
        float a = GATHER ? src[((unsigned)v) >> SHIFT] : 1.0f;
        atomicAdd(&acc[v & (CHUNK - 1)], a);
    }
    // vector body
    if (hi4 > lo4) {
        const int4* pk4 = reinterpret_cast<const int4*>(pk + lo4);
        int nvec = (hi4 - lo4) >> 2;
        for (int g = threadIdx.x; g < nvec; g += BLK) {
            int4 v = pk4[g];
            float a0 = GATHER ? src[((unsigned)v.x) >> SHIFT] : 1.0f;
            float a1 = GATHER ? src[((unsigned)v.y) >> SHIFT] : 1.0f;
            float a2 = GATHER ? src[((unsigned)v.z) >> SHIFT] : 1.0f;
            float a3 = GATHER ? src[((unsigned)v.w) >> SHIFT] : 1.0f;
            atomicAdd(&acc[v.x & (CHUNK - 1)], a0);   // ds_add_f32 (native)
            atomicAdd(&acc[v.y & (CHUNK - 1)], a1);
            atomicAdd(&acc[v.z & (CHUNK - 1)], a2);
            atomicAdd(&acc[v.w & (CHUNK - 1)], a3);
        }
    }
    // scalar tail (<=3 edges)
    {
        int tstart = (hi4 > head_end) ? hi4 : head_end;
        if (threadIdx.x < hi - tstart) {
            int v = pk[tstart + threadIdx.x];
            float a = GATHER ? src[((unsigned)v) >> SHIFT] : 1.0f;
            atomicAdd(&acc[v & (CHUNK - 1)], a);
        }
    }
    __syncthreads();
    float* out = partial + (size_t)blockIdx.x * CHUNK;
    for (int j = threadIdx.x; j < CHUNK; j += BLK) out[j] = acc[j];
}

__device__ __forceinline__ float red_sum(const float* __restrict__ partial, int i) {
    int p = i >> SHIFT, il = i & (CHUNK - 1);
    const float* base = partial + ((size_t)p * BPB) * CHUNK + il;
    float s = 0.0f;
#pragma unroll
    for (int q = 0; q < BPB; ++q) s += base[(size_t)q * CHUNK];
    return s;
}

// deg -> dis; xs -> d_out (gather source); t-self -> ws1
__global__ void k_red_deg_node1(const float* __restrict__ partial, const float* __restrict__ x,
                                float* __restrict__ dis, float* __restrict__ xs,
                                float* __restrict__ tself, int n) {
    int i = blockIdx.x * blockDim.x + threadIdx.x;
    if (i >= n) return;
    float d = rsqrtf(red_sum(partial, i) + 1.0f);   // +1 = self loop
    dis[i] = d;
    float v = x[i] * d;
    xs[i] = v;
    tself[i] = v;
}

// t = ws1 + sum; layer-2 pointwise; gs -> ws1 (gather source); u-self -> d_out
__global__ void k_red_node2(const float* __restrict__ partial, const float* __restrict__ dis,
                            float* __restrict__ t_gs, float* __restrict__ u,
                            const float* __restrict__ W1, const float* __restrict__ b1,
                            const float* __restrict__ W2, int n) {
    int i = blockIdx.x * blockDim.x + threadIdx.x;
    if (i >= n) return;
    float tt = t_gs[i] + red_sum(partial, i);
    float a = dis[i] * tt;
    float g = 0.0f;
#pragma unroll
    for (int k = 0; k < 16; ++k) {
        float h = fmaf(a, W1[k], b1[k]);
        h = fmaxf(h, 0.0f);
        g = fmaf(h, W2[k], g);
    }
    float v = g * dis[i];
    t_gs[i] = v;
    u[i]    = v;
}

// out = dis*(u-self + sum) + b2, in place on d_out
__global__ void k_red_out(const float* __restrict__ partial, const float* __restrict__ dis,
                          float* __restrict__ u_out, const float* __restrict__ b2, int n) {
    int i = blockIdx.x * blockDim.x + threadIdx.x;
    if (i >= n) return;
    float uu = u_out[i] + red_sum(partial, i);
    u_out[i] = fmaf(dis[i], uu, b2[0]);
}

// ---------- fallback path (r8: direct device atomics) ----------

__global__ void k_zero(int* __restrict__ p, int n) {
    int i = blockIdx.x * blockDim.x + threadIdx.x;
    if (i < n) p[i] = 0;
}
__global__ void k_deg(const int* __restrict__ col, int* __restrict__ deg, int E) {
    int stride = gridDim.x * blockDim.x;
    for (int e = blockIdx.x * blockDim.x + threadIdx.x; e < E; e += stride)
        atomicAdd(&deg[col[e]], 1);
}
__global__ void k_agg(const int* __restrict__ row, const int* __restrict__ col,
                      const float* __restrict__ src, float* __restrict__ dst, int E) {
    int stride = gridDim.x * blockDim.x;
    for (int e = blockIdx.x * blockDim.x + threadIdx.x; e < E; e += stride)
        unsafeAtomicAdd(&dst[col[e]], src[row[e]]);
}
__global__ void k_node1(const float* __restrict__ x, int* __restrict__ deg_i,
                        float* __restrict__ xs, float* __restrict__ t, int n) {
    int i = blockIdx.x * blockDim.x + threadIdx.x;
    if (i < n) {
        float d = rsqrtf((float)deg_i[i] + 1.0f);
        reinterpret_cast<float*>(deg_i)[i] = d;
        float v = x[i] * d;
        xs[i] = v;
        t[i]  = v;
    }
}
__global__ void k_node2(const float* __restrict__ dis, float* __restrict__ t_gs,
                        const float* __restrict__ W1, const float* __restrict__ b1,
                        const float* __restrict__ W2, float* __restrict__ u, int n) {
    int i = blockIdx.x * blockDim.x + threadIdx.x;
    if (i < n) {
        float a = dis[i] * t_gs[i];
        float g = 0.0f;
#pragma unroll
        for (int k = 0; k < 16; ++k) {
            float h = fmaf(a, W1[k], b1[k]);
            h = fmaxf(h, 0.0f);
            g = fmaf(h, W2[k], g);
        }
        float v = g * dis[i];
        t_gs[i] = v;
        u[i]    = v;
    }
}
__global__ void k_out(const float* __restrict__ dis, float* __restrict__ u_out,
                      const float* __restrict__ b2, int n) {
    int i = blockIdx.x * blockDim.x + threadIdx.x;
    if (i < n) u_out[i] = fmaf(dis[i], u_out[i], b2[0]);
}

// ---------- launch ----------

extern "C" void kernel_launch(void* const* d_in, const int* in_sizes, int n_in,
                              void* d_out, int out_size, void* d_ws, size_t ws_size,
                              hipStream_t stream) {
    const float* x   = (const float*)d_in[0];
    const int*   idx = (const int*)d_in[1];   // int64 in reference -> int32 here
    const float* W1  = (const float*)d_in[2];
    const float* b1  = (const float*)d_in[3];
    const float* W2  = (const float*)d_in[4];
    const float* b2  = (const float*)d_in[5];

    int n = in_sizes[0];
    int E = in_sizes[1] / 2;
    const int* row = idx;
    const int* col = idx + E;

    int NB = (n + CHUNK - 1) >> SHIFT;

    // workspace carve (4-byte words)
    float* wsf = (float*)d_ws;
    size_t o = 0;
    float* dis      = wsf + o;            o += (size_t)n;
    float* ws1      = wsf + o;            o += (size_t)n;
    int*   hist     = (int*)(wsf + o);    o += (size_t)NH * NB;
    int*   colOff   = (int*)(wsf + o);    o += (size_t)NH * NB;
    int*   totals   = (int*)(wsf + o);    o += (size_t)NB;
    int*   binstart = (int*)(wsf + o);    o += (size_t)NB + 1;
    o = (o + 3) & ~(size_t)3;             // 16B-align pk for int4 loads
    int*   pk       = (int*)(wsf + o);    o += (size_t)E;
    float* partial  = wsf + o;            o += (size_t)NB * BPB * CHUNK;
    bool can_bin = (NB <= MAXNB) && (ws_size >= o * 4 + 64) &&
                   (n < (1 << (31 - SHIFT))) &&   // row fits above SHIFT bits
                   ((E & 3) == 0);                // int4 alignment of col=idx+E

    float* out = (float*)d_out;           // xs -> u -> out
    int nb = (n + BLK - 1) / BLK;

    if (can_bin) {
        k_hist   <<<NH, BLK,   0, stream>>>(col, hist, E, NB);
        k_colscan<<<NB, NH,    0, stream>>>(hist, colOff, totals, NB);
        k_binscan<<<1,  MAXNB, 0, stream>>>(totals, binstart, NB);
        k_scatter<<<NH, BLK,   0, stream>>>(row, col, colOff, binstart, pk, E, NB);
        k_bagg<false><<<NB * BPB, BLK, 0, stream>>>(pk, binstart, nullptr, partial);
        k_red_deg_node1<<<nb, BLK, 0, stream>>>(partial, x, dis, out, ws1, n);
        k_bagg<true> <<<NB * BPB, BLK, 0, stream>>>(pk, binstart, out, partial);
        k_red_node2  <<<nb, BLK, 0, stream>>>(partial, dis, ws1, out, W1, b1, W2, n);
        k_bagg<true> <<<NB * BPB, BLK, 0, stream>>>(pk, binstart, ws1, partial);
        k_red_out    <<<nb, BLK, 0, stream>>>(partial, dis, out, b2, n);
    } else {
        int*   ws0i = (int*)d_ws;
        float* ws0f = (float*)d_ws;
        int eb = ((E + 3) / 4 + BLK - 1) / BLK;
        if (eb > 2048) eb = 2048;
        k_zero <<<nb, BLK, 0, stream>>>(ws0i, n);
        k_deg  <<<eb, BLK, 0, stream>>>(col, ws0i, E);
        k_node1<<<nb, BLK, 0, stream>>>(x, ws0i, out, ws1, n);
        k_agg  <<<eb, BLK, 0, stream>>>(row, col, out, ws1, E);
        k_node2<<<nb, BLK, 0, stream>>>(ws0f, ws1, W1, b1, W2, out, n);
        k_agg  <<<eb, BLK, 0, stream>>>(row, col, ws1, out, E);
        k_out  <<<nb, BLK, 0, stream>>>(ws0f, out, b2, n);
    }
}